// Round 7
// baseline (25484.807 us; speedup 1.0000x reference)
//
// LSTM 2-layer fused persistent kernel — Round 7.
// R6 post-mortem: R5==R6 at 8.2us/tick -> cost is what both share: every
// block re-reads full h/x operands via sc0sc1 MALL-bypass loads = ~24-32MB
// per tick of uncacheable replication. Fix: tick-indexed write-once chains
// so plain CACHED loads are coherent by construction (first block per XCD
// fills L2, rest hit). L1's h rides the yout fp32 chain (no 2nd 128MB buf;
// yout stores now sc0sc1 write-through so cross-XCD readers see them).
// x read cached from fp32 input (prep_xb dropped). No LDS; weights in AGPR.
// Flags unchanged: sc0sc1 poll + atomic set + in-graph memset.
// ws: flags 2MB | h1i 128KB | hs chain 128.06MB  (~130.3 MB)
#include <hip/hip_runtime.h>
#include <hip/hip_bf16.h>
#include <cstdint>
#include <cstddef>

#define T_STEPS 2048
#define BATCH   64
#define HID     512
#define BH      (BATCH * HID)     // 32768
#define NBLK    256               // 2 layers x 128 blocks (16 gate-rows each)
#define TPB     256               // 4 waves: batch split 4 x 16
#define NBLK_L  128               // blocks per layer

typedef float        f32x4 __attribute__((ext_vector_type(4)));
typedef short        s16x8 __attribute__((ext_vector_type(8)));
typedef int          i32x4 __attribute__((ext_vector_type(4)));
typedef unsigned int u32x2 __attribute__((ext_vector_type(2)));

// ---- ws offsets (bytes) ----
#define FLAGS_OFF 0x000000u   // 2 * 2048 * 128 * 4 = 2 MiB
#define H1I_OFF   0x200000u   // [64][512] f32 = 128 KiB (layer1 initial h)
#define HS_OFF    0x230000u   // [T+1][64][512] bf16 = 128.06 MiB (L0 h chain)
// end = 0x8260000 = 130.6 MB

static __device__ __forceinline__ short f2bf(float v) {
  __hip_bfloat16 b = __float2bfloat16(v);
  return *reinterpret_cast<short*>(&b);
}
static __device__ __forceinline__ float sigm(float x) {
  return 1.0f / (1.0f + __expf(-x));
}

// CACHED 16B load (L1/L2 path) with controlled issue order / vmcnt phasing
#define LOADP16(dst, base, off)                                        \
  asm volatile("global_load_dwordx4 %0, %1, off offset:%c2"            \
               : "=v"(dst) : "v"(base), "i"(off))
// publish 8B at MALL: atomic swap, no return, device scope
#define ATOMPUB8(base, val)                                            \
  asm volatile("global_atomic_swap_x2 %0, %1, off sc1"                 \
               :: "v"(base), "v"(val) : "memory")
// coherent write-through 16B store (visible at MALL for cross-XCD readers)
#define STOREC16(base, val)                                            \
  asm volatile("global_store_dwordx4 %0, %1, off sc0 sc1"              \
               :: "v"(base), "v"(val) : "memory")
#define VMDRAIN  asm volatile("s_waitcnt vmcnt(0)" ::: "memory")
#define VMWAIT32 asm volatile("s_waitcnt vmcnt(32)" ::: "memory")

#define MFMA(acc, af, bf) \
  acc = __builtin_amdgcn_mfma_f32_16x16x32_bf16(af, bf, acc, 0, 0, 0)

// spin on 4 flags (one dwordx4) until all nonzero; sc0sc1 -> reads MALL
static __device__ __forceinline__ void poll4(const int* p) {
  i32x4 v;
  for (;;) {
    asm volatile("global_load_dwordx4 %0, %1, off sc0 sc1\n\t"
                 "s_waitcnt vmcnt(0)"
                 : "=v"(v) : "v"(p) : "memory");
    if ((v[0] & v[1] & v[2] & v[3]) != 0) return;
    __builtin_amdgcn_s_sleep(1);
  }
}

__global__ void prep_h(const float* __restrict__ h0, short* __restrict__ hs,
                       float* __restrict__ h1i) {
  int idx = blockIdx.x * blockDim.x + threadIdx.x;
  if (idx >= 2 * BH) return;
  if (idx < BH) hs[idx] = f2bf(h0[idx]);   // hs chain slot 0 = L0 initial h
  else h1i[idx - BH] = h0[idx];            // L1 initial h as fp32
}

struct KArgs {
  const float* x;    // [T][B][512] fp32
  const float* c0;
  const float *Wx0, *Wh0, *bx0, *bh0;
  const float *Wx1, *Wh1, *bx1, *bh1;
  short* hs;      // [T+1][B][H] bf16 chain; slot t = L0 h at time t
  const float* h1i;  // [B][H] fp32: L1 h at t=-1
  int* flags;     // [2][T][128]
  float *yout, *hfin, *cfin;
};

template <int LAY>
static __device__ __forceinline__ void run_layer(const KArgs& a, int bidL,
                                                 int tid) {
  const int nt = tid >> 6;                        // batch tile 0..3
  const int l = tid & 63, lane15 = l & 15, jloc = l >> 4, koff = jloc * 8;
  const int row0 = bidL * 16;                     // gate-interleaved row base
  const int b = nt * 16 + lane15;                 // batch this lane owns
  const int kbase = row0 >> 2;                    // first h-col of this block
  const int kcol = kbase + jloc;                  // h-col this lane owns

  const float* WxL = LAY ? a.Wx1 : a.Wx0;
  const float* WhL = LAY ? a.Wh1 : a.Wh0;
  const float* bxL = LAY ? a.bx1 : a.bx0;
  const float* bhL = LAY ? a.bh1 : a.bh0;

  // ---- one-time: weights -> regs (compiler -> AGPR; R5-proven) ----
  // gate-interleaved row r = 4k+g ; ks<16 = Wx part, ks>=16 = Wh part
  const int r = row0 + lane15;
  const int srow = (r & 3) * HID + (r >> 2);
  s16x8 wreg[32];
#pragma unroll
  for (int ks = 0; ks < 32; ++ks) {
    const float* src = (ks < 16)
        ? (WxL + (size_t)srow * 512 + ks * 32 + koff)
        : (WhL + (size_t)srow * 512 + (ks - 16) * 32 + koff);
    f32x4 v0 = *reinterpret_cast<const f32x4*>(src);
    f32x4 v1 = *reinterpret_cast<const f32x4*>(src + 4);
    s16x8 wv;
    wv[0] = f2bf(v0[0]); wv[1] = f2bf(v0[1]); wv[2] = f2bf(v0[2]); wv[3] = f2bf(v0[3]);
    wv[4] = f2bf(v1[0]); wv[5] = f2bf(v1[1]); wv[6] = f2bf(v1[2]); wv[7] = f2bf(v1[3]);
    wreg[ks] = wv;
  }
  const float bI = bxL[kcol]           + bhL[kcol];
  const float bF = bxL[HID + kcol]     + bhL[HID + kcol];
  const float bG = bxL[2 * HID + kcol] + bhL[2 * HID + kcol];
  const float bO = bxL[3 * HID + kcol] + bhL[3 * HID + kcol];
  float c = a.c0[LAY * BH + b * HID + kcol];

  int* f0 = a.flags;                             // [T][128] layer0 flags
  int* f1 = a.flags + (size_t)T_STEPS * NBLK_L;  // layer1 flags

  for (int t = 0; t < T_STEPS; ++t) {
    // ---- wait for producers (parallel distinct-flag sc0sc1 polls) ----
    if (LAY == 0) {
      if (t > 0 && tid < 32) poll4(f0 + (size_t)(t - 1) * NBLK_L + tid * 4);
    } else {
      if (tid < 32) poll4(f0 + (size_t)t * NBLK_L + tid * 4);    // hs[t+1]
      else if (t > 0 && tid < 64)
        poll4(f1 + (size_t)(t - 1) * NBLK_L + (tid - 32) * 4);   // yout[t-1]
    }
    __syncthreads();

    f32x4 acc0 = {0.f, 0.f, 0.f, 0.f}, acc1 = {0.f, 0.f, 0.f, 0.f};
    s16x8 fragB[16];       // bf16 operand (L0: h_prev ; L1: x = hs[t+1])
    f32x4 s32[32];         // fp32 staging (L0: x_t ; L1: y_prev = h1(t-1))

    // issue bf16 chain loads first (oldest in vmcnt), then fp32 loads
    const short* bp = a.hs + (size_t)(LAY ? t + 1 : t) * BH + b * HID + koff;
#pragma unroll
    for (int i = 0; i < 16; ++i) LOADP16(fragB[i], bp, i * 64);
    const float* sp = (LAY ? (t ? a.yout + (size_t)(t - 1) * BH : a.h1i)
                           : a.x + (size_t)t * BH)
                      + b * HID + koff;
#pragma unroll
    for (int i = 0; i < 16; ++i) {
      LOADP16(s32[2 * i], sp, i * 128);
      LOADP16(s32[2 * i + 1], sp, i * 128 + 16);
    }

    VMWAIT32;                              // fragB ready (s32 in flight)
    __builtin_amdgcn_sched_barrier(0);
    // bf16-chain MFMAs: L0 -> Wh part (ks+16), L1 -> Wx part (ks)
#pragma unroll
    for (int ks = 0; ks < 16; ++ks) {
      const s16x8 wf = wreg[LAY ? ks : ks + 16];
      if (ks & 1) { MFMA(acc1, wf, fragB[ks]); } else { MFMA(acc0, wf, fragB[ks]); }
    }
    VMDRAIN;                               // s32 ready
    __builtin_amdgcn_sched_barrier(0);
#pragma unroll
    for (int ks = 0; ks < 16; ++ks) {
      f32x4 v0 = s32[2 * ks], v1 = s32[2 * ks + 1];
      s16x8 bfr;
      bfr[0] = f2bf(v0[0]); bfr[1] = f2bf(v0[1]); bfr[2] = f2bf(v0[2]); bfr[3] = f2bf(v0[3]);
      bfr[4] = f2bf(v1[0]); bfr[5] = f2bf(v1[1]); bfr[6] = f2bf(v1[2]); bfr[7] = f2bf(v1[3]);
      const s16x8 wf = wreg[LAY ? ks + 16 : ks];
      if (ks & 1) { MFMA(acc1, wf, bfr); } else { MFMA(acc0, wf, bfr); }
    }

    // lane's 4 acc regs = gates (i,f,g,o) of its (b,kcol)
    float gi = acc0[0] + acc1[0] + bI;
    float gf = acc0[1] + acc1[1] + bF;
    float gg = acc0[2] + acc1[2] + bG;
    float go = acc0[3] + acc1[3] + bO;
    float iv = sigm(gi), fv = sigm(gf);
    float gv = tanhf(gg), ov = sigm(go);
    c = fv * c + iv * gv;
    float hv = ov * tanhf(c);

    if (LAY == 0) {
      // publish bf16 h into chain slot t+1 (atomic -> lands at MALL)
      int hvi = (int)(unsigned short)f2bf(hv);
      int h1 = __shfl(hvi, lane15 + 16);
      int h2 = __shfl(hvi, lane15 + 32);
      int h3 = __shfl(hvi, lane15 + 48);
      if (jloc == 0) {
        short* dsth = a.hs + (size_t)(t + 1) * BH + b * HID + kbase;
        u32x2 pk;
        pk[0] = (unsigned)(hvi & 0xffff) | ((unsigned)h1 << 16);
        pk[1] = (unsigned)(h2 & 0xffff) | ((unsigned)h3 << 16);
        ATOMPUB8(dsth, pk);
      }
    } else {
      // publish fp32 h via yout chain (write-through so cross-XCD visible)
      int y0 = __float_as_int(hv);
      int y1 = __shfl(y0, lane15 + 16);
      int y2 = __shfl(y0, lane15 + 32);
      int y3 = __shfl(y0, lane15 + 48);
      if (jloc == 0) {
        f32x4 yv = {__int_as_float(y0), __int_as_float(y1),
                    __int_as_float(y2), __int_as_float(y3)};
        STOREC16(a.yout + (size_t)t * BH + b * HID + kbase, yv);
      }
    }
    if (t == T_STEPS - 1) {
      a.hfin[LAY * BH + b * HID + kcol] = hv;
      a.cfin[LAY * BH + b * HID + kcol] = c;
    }

    // ---- release: wait publishes ack'd, then flag (atomic at MALL) ----
    VMDRAIN;
    __syncthreads();
    if (tid == 0) {
      int one = 1;
      int* fp = (LAY ? f1 : f0) + (size_t)t * NBLK_L + bidL;
      asm volatile("global_atomic_swap %0, %1, off sc1"
                   :: "v"(fp), "v"(one) : "memory");
    }
  }
}

__global__ __launch_bounds__(TPB, 2) void lstm_fused(KArgs a) {
  const int bid = blockIdx.x;
  if (bid < NBLK_L) run_layer<0>(a, bid, threadIdx.x);
  else              run_layer<1>(a, bid - NBLK_L, threadIdx.x);
}

// ---------------- host launch ----------------
extern "C" void kernel_launch(void* const* d_in, const int* in_sizes, int n_in,
                              void* d_out, int out_size, void* d_ws, size_t ws_size,
                              hipStream_t stream) {
  const float* x   = (const float*)d_in[0];
  const float* h0  = (const float*)d_in[1];
  const float* c0  = (const float*)d_in[2];
  const float* Wx0 = (const float*)d_in[3];
  const float* Wh0 = (const float*)d_in[4];
  const float* bx0 = (const float*)d_in[5];
  const float* bh0 = (const float*)d_in[6];
  const float* Wx1 = (const float*)d_in[7];
  const float* Wh1 = (const float*)d_in[8];
  const float* bx1 = (const float*)d_in[9];
  const float* bh1 = (const float*)d_in[10];

  char* ws = (char*)d_ws;
  int*   flags = (int*)(ws + FLAGS_OFF);
  float* h1i   = (float*)(ws + H1I_OFF);
  short* hs    = (short*)(ws + HS_OFF);

  float* yout = (float*)d_out;
  float* hfin = yout + (size_t)T_STEPS * BH;
  float* cfin = hfin + 2 * BH;

  hipMemsetAsync(flags, 0, (size_t)2 * T_STEPS * NBLK_L * sizeof(int), stream);
  prep_h<<<(2 * BH + 255) / 256, 256, 0, stream>>>(h0, hs, h1i);

  KArgs ka{x, c0, Wx0, Wh0, bx0, bh0, Wx1, Wh1, bx1, bh1,
           hs, h1i, flags, yout, hfin, cfin};
  void* params[] = {&ka};
  hipLaunchCooperativeKernel((void*)lstm_fused, dim3(NBLK), dim3(TPB), params, 0,
                             stream);
}

// Round 8
// 23552.629 us; speedup vs baseline: 1.0820x; 1.0820x over previous
//
// LSTM 2-layer fused persistent kernel — Round 8.
// R7 post-mortem: cached write-once chains are CORRECT (HW-proven) but fp32
// operands on L1's critical path (yout chain + x direct) regressed perf.
// R8 = best of R5-R7 + contention cuts:
//  - counter flags: 1 fire-and-forget global_atomic_add/block/tick; consumers
//    poll ONE address (wave0 only) -> ~100x less poll traffic at MALL.
//  - hs = bf16 write-once chain, plain CACHED reads (L2-shared fills).
//  - L1 self-h = 2-slot bf16 ring, sc0sc1 bypass reads, plain sc0sc1 stores.
//  - x fp32 cached reads only on L0 (runs ahead; off critical path).
// ws: cnt 16KB | hb1 128KB | hs 128.06MB  (~128.3 MB)
#include <hip/hip_runtime.h>
#include <hip/hip_bf16.h>
#include <cstdint>
#include <cstddef>

#define T_STEPS 2048
#define BATCH   64
#define HID     512
#define BH      (BATCH * HID)     // 32768
#define NBLK    256               // 2 layers x 128 blocks (16 gate-rows each)
#define TPB     256               // 4 waves: batch split 4 x 16
#define NBLK_L  128               // blocks per layer

typedef float        f32x4 __attribute__((ext_vector_type(4)));
typedef short        s16x8 __attribute__((ext_vector_type(8)));
typedef unsigned int u32x2 __attribute__((ext_vector_type(2)));

// ---- ws offsets (bytes) ----
#define CNT_OFF   0x000000u   // [2][T] int counters = 16 KiB
#define HB1_OFF   0x010000u   // [2 parity][64][512] bf16 = 128 KiB
#define HS_OFF    0x040000u   // [T+1][64][512] bf16 = 128.06 MiB
// end = 0x8060000 = 128.4 MB

static __device__ __forceinline__ short f2bf(float v) {
  __hip_bfloat16 b = __float2bfloat16(v);
  return *reinterpret_cast<short*>(&b);
}
static __device__ __forceinline__ float sigm(float x) {
  return 1.0f / (1.0f + __expf(-x));
}

// bypass (MALL-coherent) 16B load; batch issue, wait separately
#define LOADC16(dst, base, off)                                        \
  asm volatile("global_load_dwordx4 %0, %1, off offset:%c2 sc0 sc1"    \
               : "=v"(dst) : "v"(base), "i"(off))
// coherent write-through 8B store (lands at MALL)
#define STOREC8(base, val)                                             \
  asm volatile("global_store_dwordx2 %0, %1, off sc0 sc1"              \
               :: "v"(base), "v"(val) : "memory")
#define VMDRAIN asm volatile("s_waitcnt vmcnt(0)" ::: "memory")

#define MFMA(acc, af, bf) \
  acc = __builtin_amdgcn_mfma_f32_16x16x32_bf16(af, bf, acc, 0, 0, 0)

// spin on ONE counter until it reaches `need` (bypass loads, hot spin)
static __device__ __forceinline__ void pollcnt(const int* p, int need) {
  int v;
  do {
    asm volatile("global_load_dword %0, %1, off sc0 sc1\n\t"
                 "s_waitcnt vmcnt(0)"
                 : "=v"(v) : "v"(p) : "memory");
  } while (v < need);
}

__global__ void prep_h(const float* __restrict__ h0, short* __restrict__ hs,
                       short* __restrict__ hb1) {
  int idx = blockIdx.x * blockDim.x + threadIdx.x;
  if (idx >= 2 * BH) return;
  short v = f2bf(h0[idx]);
  if (idx < BH) hs[idx] = v;          // hs chain slot 0 = L0 initial h
  else hb1[idx - BH] = v;             // hb1 parity-0 = L1 initial h
  // plain stores OK: separate kernel -> end-of-kernel L2 writeback to MALL
}

struct KArgs {
  const float* x;    // [T][B][512] fp32
  const float* c0;
  const float *Wx0, *Wh0, *bx0, *bh0;
  const float *Wx1, *Wh1, *bx1, *bh1;
  short* hs;         // [T+1][B][H] bf16 write-once chain (L0 h; L1's x-input)
  short* hb1;        // [2][B][H] bf16 ring (L1 self-h)
  int* cnt;          // [2][T] counters
  float *yout, *hfin, *cfin;
};

template <int LAY>
static __device__ __forceinline__ void run_layer(const KArgs& a, int bidL,
                                                 int tid) {
  const int nt = tid >> 6;                        // batch tile 0..3
  const int l = tid & 63, lane15 = l & 15, jloc = l >> 4, koff = jloc * 8;
  const int row0 = bidL * 16;                     // gate-interleaved row base
  const int b = nt * 16 + lane15;                 // batch this lane owns
  const int kbase = row0 >> 2;                    // first h-col of this block
  const int kcol = kbase + jloc;                  // h-col this lane owns

  const float* WxL = LAY ? a.Wx1 : a.Wx0;
  const float* WhL = LAY ? a.Wh1 : a.Wh0;
  const float* bxL = LAY ? a.bx1 : a.bx0;
  const float* bhL = LAY ? a.bh1 : a.bh0;

  // ---- one-time: weights -> regs (AGPR; R5-proven). row r = 4k+g ----
  const int r = row0 + lane15;
  const int srow = (r & 3) * HID + (r >> 2);
  s16x8 wreg[32];
#pragma unroll
  for (int ks = 0; ks < 32; ++ks) {
    const float* src = (ks < 16)
        ? (WxL + (size_t)srow * 512 + ks * 32 + koff)
        : (WhL + (size_t)srow * 512 + (ks - 16) * 32 + koff);
    f32x4 v0 = *reinterpret_cast<const f32x4*>(src);
    f32x4 v1 = *reinterpret_cast<const f32x4*>(src + 4);
    s16x8 wv;
    wv[0] = f2bf(v0[0]); wv[1] = f2bf(v0[1]); wv[2] = f2bf(v0[2]); wv[3] = f2bf(v0[3]);
    wv[4] = f2bf(v1[0]); wv[5] = f2bf(v1[1]); wv[6] = f2bf(v1[2]); wv[7] = f2bf(v1[3]);
    wreg[ks] = wv;
  }
  const float bI = bxL[kcol]           + bhL[kcol];
  const float bF = bxL[HID + kcol]     + bhL[HID + kcol];
  const float bG = bxL[2 * HID + kcol] + bhL[2 * HID + kcol];
  const float bO = bxL[3 * HID + kcol] + bhL[3 * HID + kcol];
  float c = a.c0[LAY * BH + b * HID + kcol];

  int* cnt0 = a.cnt;                 // [T] layer0 counters
  int* cnt1 = a.cnt + T_STEPS;       // [T] layer1 counters

  for (int t = 0; t < T_STEPS; ++t) {
    f32x4 acc0 = {0.f, 0.f, 0.f, 0.f}, acc1 = {0.f, 0.f, 0.f, 0.f};

    if (LAY == 0) {
      // ---- x-part first: independent of any gate (hides x fetch) ----
      const float* xp = a.x + ((size_t)t * BATCH + b) * 512 + koff;
#pragma unroll
      for (int ks = 0; ks < 16; ++ks) {
        f32x4 v0 = *reinterpret_cast<const f32x4*>(xp + ks * 32);
        f32x4 v1 = *reinterpret_cast<const f32x4*>(xp + ks * 32 + 4);
        s16x8 bfr;
        bfr[0] = f2bf(v0[0]); bfr[1] = f2bf(v0[1]); bfr[2] = f2bf(v0[2]); bfr[3] = f2bf(v0[3]);
        bfr[4] = f2bf(v1[0]); bfr[5] = f2bf(v1[1]); bfr[6] = f2bf(v1[2]); bfr[7] = f2bf(v1[3]);
        if (ks & 1) { MFMA(acc1, wreg[ks], bfr); } else { MFMA(acc0, wreg[ks], bfr); }
      }
      // ---- gate: all L0 blocks finished tick t-1 -> hs[t] complete ----
      if (t > 0) {
        if (tid < 64) pollcnt(cnt0 + t - 1, NBLK_L);
        __syncthreads();
      }
      // ---- h-part: CACHED reads of write-once chain slot t ----
      const short* hp = a.hs + (size_t)t * BH + b * HID + koff;
#pragma unroll
      for (int ks = 0; ks < 16; ++ks) {
        s16x8 f = *reinterpret_cast<const s16x8*>(hp + ks * 32);
        if (ks & 1) { MFMA(acc1, wreg[16 + ks], f); } else { MFMA(acc0, wreg[16 + ks], f); }
      }
    } else {
      // ---- gate 1: hs[t+1] ready (L0 runs ahead -> usually 1 poll iter) ----
      if (tid < 64) pollcnt(cnt0 + t, NBLK_L);
      __syncthreads();
      // ---- x-part: CACHED reads of chain slot t+1 (bf16) ----
      const short* xp = a.hs + (size_t)(t + 1) * BH + b * HID + koff;
#pragma unroll
      for (int ks = 0; ks < 16; ++ks) {
        s16x8 f = *reinterpret_cast<const s16x8*>(xp + ks * 32);
        if (ks & 1) { MFMA(acc1, wreg[ks], f); } else { MFMA(acc0, wreg[ks], f); }
      }
      // ---- gate 2: own-layer lockstep (hb1 slot ready + safe to overwrite) ----
      if (t > 0) {
        if (tid < 64) pollcnt(cnt1 + t - 1, NBLK_L);
        __syncthreads();
      }
      // ---- h-part: bypass reads of ring slot t&1 ----
      s16x8 fragH[16];
      const short* hp = a.hb1 + (t & 1) * BH + b * HID + koff;
#pragma unroll
      for (int i = 0; i < 16; ++i) LOADC16(fragH[i], hp, i * 64);
      VMDRAIN;
      __builtin_amdgcn_sched_barrier(0);
#pragma unroll
      for (int ks = 0; ks < 16; ++ks) {
        if (ks & 1) { MFMA(acc1, wreg[16 + ks], fragH[ks]); } else { MFMA(acc0, wreg[16 + ks], fragH[ks]); }
      }
    }

    // lane's 4 acc regs = gates (i,f,g,o) of its (b,kcol)
    float gi = acc0[0] + acc1[0] + bI;
    float gf = acc0[1] + acc1[1] + bF;
    float gg = acc0[2] + acc1[2] + bG;
    float go = acc0[3] + acc1[3] + bO;
    float iv = sigm(gi), fv = sigm(gf);
    float gv = tanhf(gg), ov = sigm(go);
    c = fv * c + iv * gv;
    float hv = ov * tanhf(c);

    // pack 4 consecutive kcols (jloc 0..3, same b) into jloc0 lane -> 8B store
    int hvi = (int)(unsigned short)f2bf(hv);
    int h1 = __shfl(hvi, lane15 + 16);
    int h2 = __shfl(hvi, lane15 + 32);
    int h3 = __shfl(hvi, lane15 + 48);
    short* dsth = (LAY ? a.hb1 + ((t + 1) & 1) * BH
                       : a.hs + (size_t)(t + 1) * BH)
                  + b * HID + kbase;
    if (jloc == 0) {
      u32x2 pk;
      pk[0] = (unsigned)(hvi & 0xffff) | ((unsigned)h1 << 16);
      pk[1] = (unsigned)(h2 & 0xffff) | ((unsigned)h3 << 16);
      STOREC8(dsth, pk);
    }
    if (LAY == 1) {
      int y0 = __float_as_int(hv);
      int y1 = __shfl(y0, lane15 + 16);
      int y2 = __shfl(y0, lane15 + 32);
      int y3 = __shfl(y0, lane15 + 48);
      if (jloc == 0) {
        f32x4 yv = {__int_as_float(y0), __int_as_float(y1),
                    __int_as_float(y2), __int_as_float(y3)};
        __builtin_nontemporal_store(
            yv, reinterpret_cast<f32x4*>(a.yout + ((size_t)t * BATCH + b) * HID + kbase));
      }
    }
    if (t == T_STEPS - 1) {
      a.hfin[LAY * BH + b * HID + kcol] = hv;
      a.cfin[LAY * BH + b * HID + kcol] = c;
    }

    // ---- release: drain publishes, then ONE fire-and-forget counter add ----
    VMDRAIN;
    __syncthreads();
    if (tid == 0) {
      int one = 1;
      int* cp = (LAY ? cnt1 : cnt0) + t;
      asm volatile("global_atomic_add %0, %1, off sc1"
                   :: "v"(cp), "v"(one) : "memory");
    }
  }
}

__global__ __launch_bounds__(TPB, 2) void lstm_fused(KArgs a) {
  const int bid = blockIdx.x;
  if (bid < NBLK_L) run_layer<0>(a, bid, threadIdx.x);
  else              run_layer<1>(a, bid - NBLK_L, threadIdx.x);
}

// ---------------- host launch ----------------
extern "C" void kernel_launch(void* const* d_in, const int* in_sizes, int n_in,
                              void* d_out, int out_size, void* d_ws, size_t ws_size,
                              hipStream_t stream) {
  const float* x   = (const float*)d_in[0];
  const float* h0  = (const float*)d_in[1];
  const float* c0  = (const float*)d_in[2];
  const float* Wx0 = (const float*)d_in[3];
  const float* Wh0 = (const float*)d_in[4];
  const float* bx0 = (const float*)d_in[5];
  const float* bh0 = (const float*)d_in[6];
  const float* Wx1 = (const float*)d_in[7];
  const float* Wh1 = (const float*)d_in[8];
  const float* bx1 = (const float*)d_in[9];
  const float* bh1 = (const float*)d_in[10];

  char* ws = (char*)d_ws;
  int*   cnt = (int*)(ws + CNT_OFF);
  short* hb1 = (short*)(ws + HB1_OFF);
  short* hs  = (short*)(ws + HS_OFF);

  float* yout = (float*)d_out;
  float* hfin = yout + (size_t)T_STEPS * BH;
  float* cfin = hfin + 2 * BH;

  hipMemsetAsync(cnt, 0, (size_t)2 * T_STEPS * sizeof(int), stream);
  prep_h<<<(2 * BH + 255) / 256, 256, 0, stream>>>(h0, hs, hb1);

  KArgs ka{x, c0, Wx0, Wh0, bx0, bh0, Wx1, Wh1, bx1, bh1,
           hs, hb1, cnt, yout, hfin, cfin};
  void* params[] = {&ka};
  hipLaunchCooperativeKernel((void*)lstm_fused, dim3(NBLK), dim3(TPB), params, 0,
                             stream);
}